// Round 16
// baseline (241.014 us; speedup 1.0000x reference)
//
#include <hip/hip_runtime.h>
#include <hip/hip_bf16.h>

// ---------------------------------------------------------------------------
// GraphSAGE (3x SAGEConv mean + linear head), padded-CSR formulation.
// R26 = R25 + INTRA-BLOCK aggregate->GEMM fusion (no grid sync needed):
//   The GEMM for rows [b*64,b*64+64) needs ONLY aggb rows this block can
//   produce itself. fused kernel = {phase A: aggregate own 64 nodes (exact
//   verified body, 8-node groups x 8 iters) -> aggb global (L1-hot, same
//   CU); __syncthreads(); phase B: verified 2-phase-W GEMM/head body}.
//   Removes 2 kernel boundaries + lets aggregate(block i) co-schedule with
//   GEMM(block j). 782 blocks x 4 waves, 32KB LDS -> 4 blocks/CU.
//   Unlike R9: gather keeps its own coalesced 32-lane/node pattern.
//   Unlike R24: no cooperative launch (that failed to run at all).
// R25: 217.4us (CSR trims neutral -> build path exhausted).
// R23: padded CSR -47us. R22: aggregates BW-bound at ~33us floor.
// R20 lesson: per-XCD L2s MULTIPLY a blocked working set.
// R14 lesson: GEMM B-operands from LDS. R9: no per-lane gather in GEMM.
// ---------------------------------------------------------------------------

#define DEG_SLOTS 64

typedef unsigned short bf16_t;
typedef unsigned int uint32;
typedef __attribute__((ext_vector_type(8))) short bf16x8;   // 8 bf16 = 4 VGPRs
typedef __attribute__((ext_vector_type(4))) float f32x4;

__device__ __forceinline__ bf16_t f2bf(float f) {
    uint32 u = __float_as_uint(f);
    u += 0x7fff + ((u >> 16) & 1);           // round-to-nearest-even
    return (bf16_t)(u >> 16);
}
__device__ __forceinline__ float bf2f(bf16_t b) {
    return __uint_as_float((uint32)b << 16);
}
__device__ __forceinline__ void acc8(float* acc, uint4 v) {
    acc[0] += bf2f((bf16_t)(v.x & 0xffff)); acc[1] += bf2f((bf16_t)(v.x >> 16));
    acc[2] += bf2f((bf16_t)(v.y & 0xffff)); acc[3] += bf2f((bf16_t)(v.y >> 16));
    acc[4] += bf2f((bf16_t)(v.z & 0xffff)); acc[5] += bf2f((bf16_t)(v.z >> 16));
    acc[6] += bf2f((bf16_t)(v.w & 0xffff)); acc[7] += bf2f((bf16_t)(v.w >> 16));
}

// ---- fill padded CSR, 4 edges/thread (coalesced int4 index loads) ---------
__global__ __launch_bounds__(256) void fill_padded_kernel(
    const int* __restrict__ src, const int* __restrict__ dst,
    int* __restrict__ cnt, int* __restrict__ colp, int E) {
    int i = blockIdx.x * 256 + threadIdx.x;   // quad index
    int e0 = i * 4;
    if (e0 + 3 < E) {
        int4 s = *(const int4*)&src[e0];
        int4 d = *(const int4*)&dst[e0];
        int p0 = atomicAdd(&cnt[d.x], 1);
        int p1 = atomicAdd(&cnt[d.y], 1);
        int p2 = atomicAdd(&cnt[d.z], 1);
        int p3 = atomicAdd(&cnt[d.w], 1);
        if (p0 < DEG_SLOTS) colp[d.x * DEG_SLOTS + p0] = s.x;
        if (p1 < DEG_SLOTS) colp[d.y * DEG_SLOTS + p1] = s.y;
        if (p2 < DEG_SLOTS) colp[d.z * DEG_SLOTS + p2] = s.z;
        if (p3 < DEG_SLOTS) colp[d.w * DEG_SLOTS + p3] = s.w;
    } else {
        for (int e = e0; e < E; ++e) {
            int d = dst[e];
            int pos = atomicAdd(&cnt[d], 1);
            if (pos < DEG_SLOTS) colp[d * DEG_SLOTS + pos] = src[e];
        }
    }
}

// ---- layer 1 fused: gather x-mean + MFMA (K=32) --------------------------
// 32-node blocks, one 16-row tile per wave. All 4 q-lanes gather (qh = row
// half, qe = edge parity), shfl_xor(32) combine; self-row overwrite q>=2.
// Col loads pipelined one iteration ahead (R21 +5us). Implicit rowptr.
__global__ __launch_bounds__(256) void layer16_fused_kernel(
    const float* __restrict__ x, const int* __restrict__ cnt,
    const int* __restrict__ colp,
    const float* __restrict__ Wl1, const float* __restrict__ Wr1,
    const float* __restrict__ bias, bf16_t* __restrict__ hout, int n) {
    const int t = threadIdx.x;
    const int lane = t & 63;
    const int wave = t >> 6;
    const int r = lane & 15;
    const int q = lane >> 4;
    const int qh = q & 1;
    const int qe = q >> 1;
    const int m0 = blockIdx.x * 32 + (wave >> 1) * 16;
    const int nb = (wave & 1) * 64;

    bf16x8 aF;
    {
        int node = m0 + r;
        if (node >= n) node = n - 1;
        float acc[8];
        #pragma unroll
        for (int j = 0; j < 8; ++j) acc[j] = 0.f;
        const int d = cnt[node];
        const int lo = node * DEG_SLOTS;
        const int hi = lo + d;
        int e = lo + qe;
        int c0 = 0, c1 = 0;
        if (e < hi) c0 = colp[e];
        if (e + 2 < hi) c1 = colp[e + 2];
        for (; e + 2 < hi; e += 4) {         // two edges per iter per stream
            const int p0 = c0, p1 = c1;
            if (e + 4 < hi) c0 = colp[e + 4]; // prefetch next pair; overlaps
            if (e + 6 < hi) c1 = colp[e + 6]; // with this iter's x loads
            float4 u0 = *(const float4*)&x[p0 * 16 + qh * 8];
            float4 u1 = *(const float4*)&x[p0 * 16 + qh * 8 + 4];
            float4 u2 = *(const float4*)&x[p1 * 16 + qh * 8];
            float4 u3 = *(const float4*)&x[p1 * 16 + qh * 8 + 4];
            acc[0] += u0.x + u2.x; acc[1] += u0.y + u2.y;
            acc[2] += u0.z + u2.z; acc[3] += u0.w + u2.w;
            acc[4] += u1.x + u3.x; acc[5] += u1.y + u3.y;
            acc[6] += u1.z + u3.z; acc[7] += u1.w + u3.w;
        }
        if (e < hi) {                        // at most one remainder edge;
            float4 u0 = *(const float4*)&x[c0 * 16 + qh * 8];   // c0 == colp[e]
            float4 u1 = *(const float4*)&x[c0 * 16 + qh * 8 + 4];
            acc[0] += u0.x; acc[1] += u0.y; acc[2] += u0.z; acc[3] += u0.w;
            acc[4] += u1.x; acc[5] += u1.y; acc[6] += u1.z; acc[7] += u1.w;
        }
        // combine the two edge-parity streams (lane ^ 32 flips qe, keeps r,qh)
        #pragma unroll
        for (int j = 0; j < 8; ++j) acc[j] += __shfl_xor(acc[j], 32);
        if (q < 2) {
            float iv = 1.0f / (float)max(d, 1);
            #pragma unroll
            for (int j = 0; j < 8; ++j) acc[j] *= iv;
        } else {
            // self-row half qh (K slots 16..31 of the fused K=32 fragment)
            float4 u0 = *(const float4*)&x[node * 16 + qh * 8];
            float4 u1 = *(const float4*)&x[node * 16 + qh * 8 + 4];
            acc[0] = u0.x; acc[1] = u0.y; acc[2] = u0.z; acc[3] = u0.w;
            acc[4] = u1.x; acc[5] = u1.y; acc[6] = u1.z; acc[7] = u1.w;
        }
        #pragma unroll
        for (int j = 0; j < 8; ++j) aF[j] = (short)f2bf(acc[j]);
    }

    #pragma unroll
    for (int nt = 0; nt < 4; ++nt) {
        const int cidx = nb + nt * 16 + r;
        // B-frag: K slots q*8..q*8+7 of concat(Wl1|Wr1) row cidx
        const float* wsrc = (q < 2) ? (Wl1 + cidx * 16 + qh * 8)
                                    : (Wr1 + cidx * 16 + qh * 8);
        float4 w0 = *(const float4*)wsrc;
        float4 w1 = *(const float4*)(wsrc + 4);
        bf16x8 bF;
        bF[0] = (short)f2bf(w0.x); bF[1] = (short)f2bf(w0.y);
        bF[2] = (short)f2bf(w0.z); bF[3] = (short)f2bf(w0.w);
        bF[4] = (short)f2bf(w1.x); bF[5] = (short)f2bf(w1.y);
        bF[6] = (short)f2bf(w1.z); bF[7] = (short)f2bf(w1.w);
        f32x4 acc0 = {0.f, 0.f, 0.f, 0.f};
        acc0 = __builtin_amdgcn_mfma_f32_16x16x32_bf16(aF, bF, acc0, 0, 0, 0);
        float bo = bias[cidx];
        #pragma unroll
        for (int reg = 0; reg < 4; ++reg) {
            int row0 = m0 + q * 4 + reg;
            if (row0 < n)
                hout[(size_t)row0 * 128 + cidx] = f2bf(fmaxf(acc0[reg] + bo, 0.0f));
        }
    }
}

// ---- mean-aggregate 8 nodes with 256 threads (verified R22/R25 body) ------
// 32 lanes/node = 2 edge-parity streams x 16 dim-lanes; col prefetched one
// iteration ahead; shfl_xor(16) combine; sub==0 half stores bf16 to aggb.
__device__ __forceinline__ void aggregate8(
    int nbase8, const bf16_t* __restrict__ h, const int* __restrict__ cnt,
    const int* __restrict__ colp, bf16_t* __restrict__ aggb, int N) {
    const int t = threadIdx.x;
    const int node = nbase8 + (t >> 5);
    const int sub = (t >> 4) & 1;
    const int li = t & 15;
    if (node >= N) return;
    const int d = cnt[node];
    const int lo = node * DEG_SLOTS;
    const int hi = lo + d;
    float acc[8];
    #pragma unroll
    for (int j = 0; j < 8; ++j) acc[j] = 0.0f;
    int e = lo + sub;
    int c0 = 0, c1 = 0, c2 = 0, c3 = 0;
    if (e < hi)     c0 = colp[e];
    if (e + 2 < hi) c1 = colp[e + 2];
    if (e + 4 < hi) c2 = colp[e + 4];
    if (e + 6 < hi) c3 = colp[e + 6];
    for (; e + 6 < hi; e += 8) {
        const int s0 = c0, s1 = c1, s2 = c2, s3 = c3;
        if (e + 8  < hi) c0 = colp[e + 8];
        if (e + 10 < hi) c1 = colp[e + 10];
        if (e + 12 < hi) c2 = colp[e + 12];
        if (e + 14 < hi) c3 = colp[e + 14];
        uint4 v0 = *(const uint4*)&h[(size_t)s0 * 128 + li * 8];
        uint4 v1 = *(const uint4*)&h[(size_t)s1 * 128 + li * 8];
        uint4 v2 = *(const uint4*)&h[(size_t)s2 * 128 + li * 8];
        uint4 v3 = *(const uint4*)&h[(size_t)s3 * 128 + li * 8];
        acc8(acc, v0);
        acc8(acc, v1);
        acc8(acc, v2);
        acc8(acc, v3);
    }
    if (e < hi) {
        uint4 v = *(const uint4*)&h[(size_t)c0 * 128 + li * 8];
        acc8(acc, v);
    }
    if (e + 2 < hi) {
        uint4 v = *(const uint4*)&h[(size_t)c1 * 128 + li * 8];
        acc8(acc, v);
    }
    if (e + 4 < hi) {
        uint4 v = *(const uint4*)&h[(size_t)c2 * 128 + li * 8];
        acc8(acc, v);
    }
    #pragma unroll
    for (int j = 0; j < 8; ++j) acc[j] += __shfl_xor(acc[j], 16);
    if (sub == 0) {
        const float iv = 1.0f / (float)max(d, 1);
        uint4 pk;
        pk.x = (uint32)f2bf(acc[0] * iv) | ((uint32)f2bf(acc[1] * iv) << 16);
        pk.y = (uint32)f2bf(acc[2] * iv) | ((uint32)f2bf(acc[3] * iv) << 16);
        pk.z = (uint32)f2bf(acc[4] * iv) | ((uint32)f2bf(acc[5] * iv) << 16);
        pk.w = (uint32)f2bf(acc[6] * iv) | ((uint32)f2bf(acc[7] * iv) << 16);
        *(uint4*)&aggb[(size_t)node * 128 + li * 8] = pk;
    }
}

// ---- fused layer 2: per-block aggregate -> 2-phase-W GEMM -----------------
// Block = 64 rows x ALL 128 cols. Phase A aggregates the block's own 64
// nodes into aggb (L1/L2-hot round trip, same CU). Phase B = verified
// 2-phase W-staged GEMM (R25 head structure minus head), writes hout.
__global__ __launch_bounds__(256) void fused_agg_gemm_kernel(
    const bf16_t* __restrict__ hin, const int* __restrict__ cnt,
    const int* __restrict__ colp,
    const float* __restrict__ Wl, const float* __restrict__ Wr,
    const float* __restrict__ bias,
    bf16_t* __restrict__ aggb, bf16_t* __restrict__ hout, int n) {
    __shared__ bf16_t w_lds[16384];          // 32KB

    const int t = threadIdx.x;
    const int lane = t & 63;
    const int wave = t >> 6;
    const int r = lane & 15;
    const int q = lane >> 4;
    const int nb0 = blockIdx.x * 64;

    // phase A: aggregate own 64 nodes
    #pragma unroll
    for (int i = 0; i < 8; ++i)
        aggregate8(nb0 + i * 8, hin, cnt, colp, aggb, n);
    __syncthreads();                         // aggb visible block-wide (same CU L1)

    // phase B: GEMM, one 16-row M-frag per wave, 128 cols via 2 W phases
    const int m0w = nb0 + wave * 16;
    bf16x8 aF[8];
    {
        int node = m0w + r;
        if (node >= n) node = n - 1;
        const bf16_t* arow = aggb + (size_t)node * 128;
        const bf16_t* hrow = hin + (size_t)node * 128;
        #pragma unroll
        for (int ks = 0; ks < 4; ++ks)
            aF[ks] = *(const bf16x8*)(arow + ks * 32 + q * 8);
        #pragma unroll
        for (int ks = 0; ks < 4; ++ks)
            aF[4 + ks] = *(const bf16x8*)(hrow + ks * 32 + q * 8);
    }

    #pragma unroll
    for (int phase = 0; phase < 2; ++phase) {
        if (phase) __syncthreads();          // all reads of phase-0 W done
        const int nbase = phase * 64;
        #pragma unroll
        for (int i = 0; i < 8; ++i) {
            int ch  = i * 256 + t;
            int q_  = ch & 3;
            int r_  = (ch >> 2) & 15;
            int ks_ = (ch >> 6) & 7;
            int nt_ = ch >> 9;
            int cidx = nbase + nt_ * 16 + r_;
            int k0 = ks_ * 32 + q_ * 8;
            const float* src = (k0 < 128) ? (Wl + cidx * 128 + k0)
                                          : (Wr + cidx * 128 + (k0 - 128));
            float4 a = *(const float4*)src;
            float4 b = *(const float4*)(src + 4);
            uint4 pk;
            pk.x = (uint32)f2bf(a.x) | ((uint32)f2bf(a.y) << 16);
            pk.y = (uint32)f2bf(a.z) | ((uint32)f2bf(a.w) << 16);
            pk.z = (uint32)f2bf(b.x) | ((uint32)f2bf(b.y) << 16);
            pk.w = (uint32)f2bf(b.z) | ((uint32)f2bf(b.w) << 16);
            *(uint4*)&w_lds[ch * 8] = pk;
        }
        __syncthreads();

        #pragma unroll
        for (int nt = 0; nt < 4; ++nt) {
            f32x4 acc0 = {0.f, 0.f, 0.f, 0.f};
            #pragma unroll
            for (int ks = 0; ks < 8; ++ks) {
                bf16x8 bF = *(const bf16x8*)&w_lds[(size_t)((nt * 8 + ks) * 64 + r * 4 + q) * 8];
                acc0 = __builtin_amdgcn_mfma_f32_16x16x32_bf16(aF[ks], bF, acc0, 0, 0, 0);
            }
            const int cidx = nbase + nt * 16 + r;
            const float bo = bias[cidx];
            #pragma unroll
            for (int reg = 0; reg < 4; ++reg) {
                int row = m0w + q * 4 + reg;
                if (row < n)
                    hout[(size_t)row * 128 + cidx] = f2bf(fmaxf(acc0[reg] + bo, 0.0f));
            }
        }
    }
}

// ---- fused layer 3 + head: per-block aggregate -> GEMM+head ---------------
// Same as fused_agg_gemm but layer-3 output feeds the head in-register
// (verified R25 head epilogue); out written directly, h3 never hits global.
__global__ __launch_bounds__(256) void fused_agg_head_kernel(
    const bf16_t* __restrict__ hin, const int* __restrict__ cnt,
    const int* __restrict__ colp,
    const float* __restrict__ Wl, const float* __restrict__ Wr,
    const float* __restrict__ bias, const float* __restrict__ Wh,
    const float* __restrict__ bh,
    bf16_t* __restrict__ aggb, float* __restrict__ out, int n) {
    __shared__ bf16_t w_lds[16384];          // 32KB

    const int t = threadIdx.x;
    const int lane = t & 63;
    const int wave = t >> 6;
    const int r = lane & 15;
    const int q = lane >> 4;
    const int nb0 = blockIdx.x * 64;

    // phase A: aggregate own 64 nodes
    #pragma unroll
    for (int i = 0; i < 8; ++i)
        aggregate8(nb0 + i * 8, hin, cnt, colp, aggb, n);
    __syncthreads();

    // phase B: GEMM + head partials
    const int m0w = nb0 + wave * 16;
    bf16x8 aF[8];
    {
        int node = m0w + r;
        if (node >= n) node = n - 1;
        const bf16_t* arow = aggb + (size_t)node * 128;
        const bf16_t* hrow = hin + (size_t)node * 128;
        #pragma unroll
        for (int ks = 0; ks < 4; ++ks)
            aF[ks] = *(const bf16x8*)(arow + ks * 32 + q * 8);
        #pragma unroll
        for (int ks = 0; ks < 4; ++ks)
            aF[4 + ks] = *(const bf16x8*)(hrow + ks * 32 + q * 8);
    }

    float p[4][4];                           // [reg][o] head partials
    #pragma unroll
    for (int reg = 0; reg < 4; ++reg)
        #pragma unroll
        for (int o = 0; o < 4; ++o) p[reg][o] = 0.f;

    #pragma unroll
    for (int phase = 0; phase < 2; ++phase) {
        if (phase) __syncthreads();          // all reads of phase-0 W done
        const int nbase = phase * 64;
        #pragma unroll
        for (int i = 0; i < 8; ++i) {
            int ch  = i * 256 + t;
            int q_  = ch & 3;
            int r_  = (ch >> 2) & 15;
            int ks_ = (ch >> 6) & 7;
            int nt_ = ch >> 9;
            int cidx = nbase + nt_ * 16 + r_;
            int k0 = ks_ * 32 + q_ * 8;
            const float* src = (k0 < 128) ? (Wl + cidx * 128 + k0)
                                          : (Wr + cidx * 128 + (k0 - 128));
            float4 a = *(const float4*)src;
            float4 b = *(const float4*)(src + 4);
            uint4 pk;
            pk.x = (uint32)f2bf(a.x) | ((uint32)f2bf(a.y) << 16);
            pk.y = (uint32)f2bf(a.z) | ((uint32)f2bf(a.w) << 16);
            pk.z = (uint32)f2bf(b.x) | ((uint32)f2bf(b.y) << 16);
            pk.w = (uint32)f2bf(b.z) | ((uint32)f2bf(b.w) << 16);
            *(uint4*)&w_lds[ch * 8] = pk;
        }
        __syncthreads();

        #pragma unroll
        for (int nt = 0; nt < 4; ++nt) {
            f32x4 acc0 = {0.f, 0.f, 0.f, 0.f};
            #pragma unroll
            for (int ks = 0; ks < 8; ++ks) {
                bf16x8 bF = *(const bf16x8*)&w_lds[(size_t)((nt * 8 + ks) * 64 + r * 4 + q) * 8];
                acc0 = __builtin_amdgcn_mfma_f32_16x16x32_bf16(aF[ks], bF, acc0, 0, 0, 0);
            }
            const int cidx = nbase + nt * 16 + r;
            const float bo = bias[cidx];
            const float wh0 = Wh[cidx], wh1 = Wh[128 + cidx];
            const float wh2 = Wh[256 + cidx], wh3 = Wh[384 + cidx];
            #pragma unroll
            for (int reg = 0; reg < 4; ++reg) {
                float h0 = fmaxf(acc0[reg] + bo, 0.0f);
                p[reg][0] += h0 * wh0; p[reg][1] += h0 * wh1;
                p[reg][2] += h0 * wh2; p[reg][3] += h0 * wh3;
            }
        }
    }

    // close the col-dot: reduce over the 16 r-lanes; r==0 writes 4 outs/row
    #pragma unroll
    for (int reg = 0; reg < 4; ++reg)
        #pragma unroll
        for (int o = 0; o < 4; ++o) {
            float v = p[reg][o];
            v += __shfl_xor(v, 1);
            v += __shfl_xor(v, 2);
            v += __shfl_xor(v, 4);
            v += __shfl_xor(v, 8);
            if (r == 0) {
                int row = m0w + q * 4 + reg;
                if (row < n) out[(size_t)row * 4 + o] = v + bh[o];
            }
        }
}

extern "C" void kernel_launch(void* const* d_in, const int* in_sizes, int n_in,
                              void* d_out, int out_size, void* d_ws, size_t ws_size,
                              hipStream_t stream) {
    const float* x   = (const float*)d_in[0];
    const int*   ei  = (const int*)d_in[1];
    const float* Wl1 = (const float*)d_in[2];
    const float* Wr1 = (const float*)d_in[3];
    const float* b1  = (const float*)d_in[4];
    const float* Wl2 = (const float*)d_in[5];
    const float* Wr2 = (const float*)d_in[6];
    const float* b2  = (const float*)d_in[7];
    const float* Wl3 = (const float*)d_in[8];
    const float* Wr3 = (const float*)d_in[9];
    const float* b3  = (const float*)d_in[10];
    const float* Wh  = (const float*)d_in[11];
    const float* bh  = (const float*)d_in[12];
    float* out = (float*)d_out;

    const int N = in_sizes[0] / 16;
    const int E = in_sizes[1] / 2;
    const int* src = ei;
    const int* dst = ei + E;

    int* cnt       = (int*)d_ws;                       // N
    int* colp      = cnt + ((N + 64) & ~63);           // N*DEG_SLOTS (aligned)
    bf16_t* aggb   = (bf16_t*)(colp + (size_t)N * DEG_SLOTS);  // N*128 bf16
    bf16_t* hA     = aggb + (size_t)N * 128;           // N*128 bf16
    bf16_t* hB     = hA + (size_t)N * 128;             // N*128 bf16

    const int B = 256;
    auto blocks = [](long total, int b) { return (int)((total + b - 1) / b); };

    // ---- padded CSR build: async memset + vectorized fill ----
    hipMemsetAsync(cnt, 0, (size_t)N * sizeof(int), stream);
    fill_padded_kernel<<<blocks((E + 3) / 4, B), B, 0, stream>>>(src, dst, cnt, colp, E);

    // ---- layer 1: fused x-gather + MFMA (K=32), writes hA ----
    layer16_fused_kernel<<<blocks(N, 32), B, 0, stream>>>(
        x, cnt, colp, Wl1, Wr1, b1, hA, N);

    // ---- layer 2: fused aggregate + GEMM, writes hB ----
    fused_agg_gemm_kernel<<<blocks(N, 64), B, 0, stream>>>(
        hA, cnt, colp, Wl2, Wr2, b2, aggb, hB, N);

    // ---- layer 3: fused aggregate + GEMM + head, writes out ----
    fused_agg_head_kernel<<<blocks(N, 64), B, 0, stream>>>(
        hB, cnt, colp, Wl3, Wr3, b3, Wh, bh, aggb, out, N);
}

// Round 17
// 215.486 us; speedup vs baseline: 1.1185x; 1.1185x over previous
//
#include <hip/hip_runtime.h>
#include <hip/hip_bf16.h>

// ---------------------------------------------------------------------------
// GraphSAGE (3x SAGEConv mean + linear head), padded-CSR formulation.
// R27 = R25 reverted verbatim (verified 217.4us).
// R26 post-mortem: intra-block agg->GEMM fusion FALSIFIED — fused kernel
// 76us @ 19% occupancy (32KB LDS capped residency; BW-bound aggregate
// needs ~32 waves/CU, got ~6) + 800K bank conflicts + per-block sync tail.
// Third confirmation: aggregates are request-rate-bound and MUST run in a
// dedicated max-occupancy kernel (R9: fuse-into-GEMM bad; R24: cooperative
// mega-kernel never ran; R26: fuse-around-GEMM bad).
// Session floor arithmetic at 217us: 2x aggregate ~66us (4.7 TB/s random-
// 256B L3 ceiling — blocking falsified R20, prefetch neutral R22), fill
// ~25us (atomic/scatter-bound, vectorization neutral R25), layer16 ~15us
// (chain-pipelined R21), GEMMs ~20us (LDS-staged), ~5 boundaries ~20us.
// R14 lesson: GEMM B-operands from LDS. R23: padded CSR killed scan/count.
// ---------------------------------------------------------------------------

#define DEG_SLOTS 64

typedef unsigned short bf16_t;
typedef unsigned int uint32;
typedef __attribute__((ext_vector_type(8))) short bf16x8;   // 8 bf16 = 4 VGPRs
typedef __attribute__((ext_vector_type(4))) float f32x4;

__device__ __forceinline__ bf16_t f2bf(float f) {
    uint32 u = __float_as_uint(f);
    u += 0x7fff + ((u >> 16) & 1);           // round-to-nearest-even
    return (bf16_t)(u >> 16);
}
__device__ __forceinline__ float bf2f(bf16_t b) {
    return __uint_as_float((uint32)b << 16);
}
__device__ __forceinline__ void acc8(float* acc, uint4 v) {
    acc[0] += bf2f((bf16_t)(v.x & 0xffff)); acc[1] += bf2f((bf16_t)(v.x >> 16));
    acc[2] += bf2f((bf16_t)(v.y & 0xffff)); acc[3] += bf2f((bf16_t)(v.y >> 16));
    acc[4] += bf2f((bf16_t)(v.z & 0xffff)); acc[5] += bf2f((bf16_t)(v.z >> 16));
    acc[6] += bf2f((bf16_t)(v.w & 0xffff)); acc[7] += bf2f((bf16_t)(v.w >> 16));
}

// ---- fill padded CSR, 4 edges/thread (coalesced int4 index loads) ---------
__global__ __launch_bounds__(256) void fill_padded_kernel(
    const int* __restrict__ src, const int* __restrict__ dst,
    int* __restrict__ cnt, int* __restrict__ colp, int E) {
    int i = blockIdx.x * 256 + threadIdx.x;   // quad index
    int e0 = i * 4;
    if (e0 + 3 < E) {
        int4 s = *(const int4*)&src[e0];
        int4 d = *(const int4*)&dst[e0];
        int p0 = atomicAdd(&cnt[d.x], 1);
        int p1 = atomicAdd(&cnt[d.y], 1);
        int p2 = atomicAdd(&cnt[d.z], 1);
        int p3 = atomicAdd(&cnt[d.w], 1);
        if (p0 < DEG_SLOTS) colp[d.x * DEG_SLOTS + p0] = s.x;
        if (p1 < DEG_SLOTS) colp[d.y * DEG_SLOTS + p1] = s.y;
        if (p2 < DEG_SLOTS) colp[d.z * DEG_SLOTS + p2] = s.z;
        if (p3 < DEG_SLOTS) colp[d.w * DEG_SLOTS + p3] = s.w;
    } else {
        for (int e = e0; e < E; ++e) {
            int d = dst[e];
            int pos = atomicAdd(&cnt[d], 1);
            if (pos < DEG_SLOTS) colp[d * DEG_SLOTS + pos] = src[e];
        }
    }
}

// ---- layer 1 fused: gather x-mean + MFMA (K=32) --------------------------
// 32-node blocks, one 16-row tile per wave. All 4 q-lanes gather (qh = row
// half, qe = edge parity), shfl_xor(32) combine; self-row overwrite q>=2.
// Col loads pipelined one iteration ahead (R21, +5us validated).
// Implicit rowptr (lo = node*64), deg from cnt, inv inline.
__global__ __launch_bounds__(256) void layer16_fused_kernel(
    const float* __restrict__ x, const int* __restrict__ cnt,
    const int* __restrict__ colp,
    const float* __restrict__ Wl1, const float* __restrict__ Wr1,
    const float* __restrict__ bias, bf16_t* __restrict__ hout, int n) {
    const int t = threadIdx.x;
    const int lane = t & 63;
    const int wave = t >> 6;
    const int r = lane & 15;
    const int q = lane >> 4;
    const int qh = q & 1;
    const int qe = q >> 1;
    const int m0 = blockIdx.x * 32 + (wave >> 1) * 16;
    const int nb = (wave & 1) * 64;

    bf16x8 aF;
    {
        int node = m0 + r;
        if (node >= n) node = n - 1;
        float acc[8];
        #pragma unroll
        for (int j = 0; j < 8; ++j) acc[j] = 0.f;
        const int d = cnt[node];
        const int lo = node * DEG_SLOTS;
        const int hi = lo + d;
        int e = lo + qe;
        int c0 = 0, c1 = 0;
        if (e < hi) c0 = colp[e];
        if (e + 2 < hi) c1 = colp[e + 2];
        for (; e + 2 < hi; e += 4) {         // two edges per iter per stream
            const int p0 = c0, p1 = c1;
            if (e + 4 < hi) c0 = colp[e + 4]; // prefetch next pair; overlaps
            if (e + 6 < hi) c1 = colp[e + 6]; // with this iter's x loads
            float4 u0 = *(const float4*)&x[p0 * 16 + qh * 8];
            float4 u1 = *(const float4*)&x[p0 * 16 + qh * 8 + 4];
            float4 u2 = *(const float4*)&x[p1 * 16 + qh * 8];
            float4 u3 = *(const float4*)&x[p1 * 16 + qh * 8 + 4];
            acc[0] += u0.x + u2.x; acc[1] += u0.y + u2.y;
            acc[2] += u0.z + u2.z; acc[3] += u0.w + u2.w;
            acc[4] += u1.x + u3.x; acc[5] += u1.y + u3.y;
            acc[6] += u1.z + u3.z; acc[7] += u1.w + u3.w;
        }
        if (e < hi) {                        // at most one remainder edge;
            float4 u0 = *(const float4*)&x[c0 * 16 + qh * 8];   // c0 == colp[e]
            float4 u1 = *(const float4*)&x[c0 * 16 + qh * 8 + 4];
            acc[0] += u0.x; acc[1] += u0.y; acc[2] += u0.z; acc[3] += u0.w;
            acc[4] += u1.x; acc[5] += u1.y; acc[6] += u1.z; acc[7] += u1.w;
        }
        // combine the two edge-parity streams (lane ^ 32 flips qe, keeps r,qh)
        #pragma unroll
        for (int j = 0; j < 8; ++j) acc[j] += __shfl_xor(acc[j], 32);
        if (q < 2) {
            float iv = 1.0f / (float)max(d, 1);
            #pragma unroll
            for (int j = 0; j < 8; ++j) acc[j] *= iv;
        } else {
            // self-row half qh (K slots 16..31 of the fused K=32 fragment)
            float4 u0 = *(const float4*)&x[node * 16 + qh * 8];
            float4 u1 = *(const float4*)&x[node * 16 + qh * 8 + 4];
            acc[0] = u0.x; acc[1] = u0.y; acc[2] = u0.z; acc[3] = u0.w;
            acc[4] = u1.x; acc[5] = u1.y; acc[6] = u1.z; acc[7] = u1.w;
        }
        #pragma unroll
        for (int j = 0; j < 8; ++j) aF[j] = (short)f2bf(acc[j]);
    }

    #pragma unroll
    for (int nt = 0; nt < 4; ++nt) {
        const int cidx = nb + nt * 16 + r;
        // B-frag: K slots q*8..q*8+7 of concat(Wl1|Wr1) row cidx
        const float* wsrc = (q < 2) ? (Wl1 + cidx * 16 + qh * 8)
                                    : (Wr1 + cidx * 16 + qh * 8);
        float4 w0 = *(const float4*)wsrc;
        float4 w1 = *(const float4*)(wsrc + 4);
        bf16x8 bF;
        bF[0] = (short)f2bf(w0.x); bF[1] = (short)f2bf(w0.y);
        bF[2] = (short)f2bf(w0.z); bF[3] = (short)f2bf(w0.w);
        bF[4] = (short)f2bf(w1.x); bF[5] = (short)f2bf(w1.y);
        bF[6] = (short)f2bf(w1.z); bF[7] = (short)f2bf(w1.w);
        f32x4 acc0 = {0.f, 0.f, 0.f, 0.f};
        acc0 = __builtin_amdgcn_mfma_f32_16x16x32_bf16(aF, bF, acc0, 0, 0, 0);
        float bo = bias[cidx];
        #pragma unroll
        for (int reg = 0; reg < 4; ++reg) {
            int row0 = m0 + q * 4 + reg;
            if (row0 < n)
                hout[(size_t)row0 * 128 + cidx] = f2bf(fmaxf(acc0[reg] + bo, 0.0f));
        }
    }
}

// ---- high-occupancy coalesced mean aggregate ------------------------------
// 32 lanes/node = 2 edge-parity streams x 16 dim-lanes (16B each).
// Col indices prefetched one iteration ahead. Implicit rowptr, inv inline.
// Streams combined via one shfl_xor(16); sub==0 half stores. BW-bound at
// ~4.7 TB/s random-L3 (the floor; blocking falsified R20, fusion R26).
__global__ __launch_bounds__(256) void aggregate128_kernel(
    const bf16_t* __restrict__ h, const int* __restrict__ cnt,
    const int* __restrict__ colp,
    bf16_t* __restrict__ aggb, int N) {
    const int t = threadIdx.x;
    const int node = blockIdx.x * 8 + (t >> 5);
    const int sub = (t >> 4) & 1;            // edge-parity stream
    const int li = t & 15;                   // 8-bf16 (16B) column slot
    if (node >= N) return;
    const int d = cnt[node];
    const int lo = node * DEG_SLOTS;
    const int hi = lo + d;
    float acc[8];
    #pragma unroll
    for (int j = 0; j < 8; ++j) acc[j] = 0.0f;
    int e = lo + sub;
    int c0 = 0, c1 = 0, c2 = 0, c3 = 0;
    if (e < hi)     c0 = colp[e];
    if (e + 2 < hi) c1 = colp[e + 2];
    if (e + 4 < hi) c2 = colp[e + 4];
    if (e + 6 < hi) c3 = colp[e + 6];
    for (; e + 6 < hi; e += 8) {             // 4 edges per iter per stream
        const int s0 = c0, s1 = c1, s2 = c2, s3 = c3;
        if (e + 8  < hi) c0 = colp[e + 8];   // prefetch next quad; overlaps
        if (e + 10 < hi) c1 = colp[e + 10];  // with this iter's row loads
        if (e + 12 < hi) c2 = colp[e + 12];
        if (e + 14 < hi) c3 = colp[e + 14];
        uint4 v0 = *(const uint4*)&h[(size_t)s0 * 128 + li * 8];
        uint4 v1 = *(const uint4*)&h[(size_t)s1 * 128 + li * 8];
        uint4 v2 = *(const uint4*)&h[(size_t)s2 * 128 + li * 8];
        uint4 v3 = *(const uint4*)&h[(size_t)s3 * 128 + li * 8];
        acc8(acc, v0);
        acc8(acc, v1);
        acc8(acc, v2);
        acc8(acc, v3);
    }
    // remainder (<=3 rows), indices already prefetched into c0..c2
    if (e < hi) {
        uint4 v = *(const uint4*)&h[(size_t)c0 * 128 + li * 8];
        acc8(acc, v);
    }
    if (e + 2 < hi) {
        uint4 v = *(const uint4*)&h[(size_t)c1 * 128 + li * 8];
        acc8(acc, v);
    }
    if (e + 4 < hi) {
        uint4 v = *(const uint4*)&h[(size_t)c2 * 128 + li * 8];
        acc8(acc, v);
    }
    // combine streams: lane ^ 16 flips sub, keeps li and node
    #pragma unroll
    for (int j = 0; j < 8; ++j) acc[j] += __shfl_xor(acc[j], 16);
    if (sub == 0) {
        const float iv = 1.0f / (float)max(d, 1);
        uint4 pk;
        pk.x = (uint32)f2bf(acc[0] * iv) | ((uint32)f2bf(acc[1] * iv) << 16);
        pk.y = (uint32)f2bf(acc[2] * iv) | ((uint32)f2bf(acc[3] * iv) << 16);
        pk.z = (uint32)f2bf(acc[4] * iv) | ((uint32)f2bf(acc[5] * iv) << 16);
        pk.w = (uint32)f2bf(acc[6] * iv) | ((uint32)f2bf(acc[7] * iv) << 16);
        *(uint4*)&aggb[(size_t)node * 128 + li * 8] = pk;
    }
}

// ---- layer 2: MFMA bf16 GEMM, K=256, LDS-staged + converted weights -------
// Block = 128 rows x 64 cols (col half c = bid&1). W half staged fragment-
// major with inline fp32->bf16 convert (chunk = (nt*8+ks)*64 + r*4 + q; a
// wave's ds_read_b128 at fixed (nt,ks) is a lane-bijective 1024B span).
__global__ __launch_bounds__(256) void layer128_mfma_kernel(
    const bf16_t* __restrict__ aggb, const bf16_t* __restrict__ hin,
    const float* __restrict__ Wl, const float* __restrict__ Wr,
    const float* __restrict__ bias, bf16_t* __restrict__ hout, int n) {
    __shared__ bf16_t w_lds[16384];          // 32KB

    const int t = threadIdx.x;
    const int lane = t & 63;
    const int wave = t >> 6;
    const int r = lane & 15;
    const int q = lane >> 4;
    const int c = blockIdx.x & 1;
    const int rowblk = blockIdx.x >> 1;
    const int nbase = c * 64;
    const int m0w = rowblk * 128 + wave * 32;

    // stage + convert W half, fragment-major (2048 x 16B chunks, 8/thread)
    #pragma unroll
    for (int i = 0; i < 8; ++i) {
        int ch  = i * 256 + t;
        int q_  = ch & 3;
        int r_  = (ch >> 2) & 15;
        int ks_ = (ch >> 6) & 7;
        int nt_ = ch >> 9;
        int cidx = nbase + nt_ * 16 + r_;
        int k0 = ks_ * 32 + q_ * 8;
        const float* src = (k0 < 128) ? (Wl + cidx * 128 + k0)
                                      : (Wr + cidx * 128 + (k0 - 128));
        float4 a = *(const float4*)src;
        float4 b = *(const float4*)(src + 4);
        uint4 pk;
        pk.x = (uint32)f2bf(a.x) | ((uint32)f2bf(a.y) << 16);
        pk.y = (uint32)f2bf(a.z) | ((uint32)f2bf(a.w) << 16);
        pk.z = (uint32)f2bf(b.x) | ((uint32)f2bf(b.y) << 16);
        pk.w = (uint32)f2bf(b.z) | ((uint32)f2bf(b.w) << 16);
        *(uint4*)&w_lds[ch * 8] = pk;
    }

    // A fragments (global, independent; overlap LDS staging)
    bf16x8 aF[2][8];
    #pragma unroll
    for (int mt = 0; mt < 2; ++mt) {
        int node = m0w + mt * 16 + r;
        if (node >= n) node = n - 1;
        const bf16_t* arow = aggb + (size_t)node * 128;
        const bf16_t* hrow = hin + (size_t)node * 128;
        #pragma unroll
        for (int ks = 0; ks < 4; ++ks)
            aF[mt][ks] = *(const bf16x8*)(arow + ks * 32 + q * 8);
        #pragma unroll
        for (int ks = 0; ks < 4; ++ks)
            aF[mt][4 + ks] = *(const bf16x8*)(hrow + ks * 32 + q * 8);
    }
    __syncthreads();

    #pragma unroll
    for (int nt = 0; nt < 4; ++nt) {
        f32x4 acc0 = {0.f, 0.f, 0.f, 0.f};
        f32x4 acc1 = {0.f, 0.f, 0.f, 0.f};
        #pragma unroll
        for (int ks = 0; ks < 8; ++ks) {
            bf16x8 bF = *(const bf16x8*)&w_lds[(size_t)((nt * 8 + ks) * 64 + r * 4 + q) * 8];
            acc0 = __builtin_amdgcn_mfma_f32_16x16x32_bf16(aF[0][ks], bF, acc0, 0, 0, 0);
            acc1 = __builtin_amdgcn_mfma_f32_16x16x32_bf16(aF[1][ks], bF, acc1, 0, 0, 0);
        }
        const int cidx = nbase + nt * 16 + r;
        const float bo = bias[cidx];
        #pragma unroll
        for (int reg = 0; reg < 4; ++reg) {
            int row0 = m0w + q * 4 + reg;
            if (row0 < n)
                hout[(size_t)row0 * 128 + cidx] = f2bf(fmaxf(acc0[reg] + bo, 0.0f));
            int row1 = m0w + 16 + q * 4 + reg;
            if (row1 < n)
                hout[(size_t)row1 * 128 + cidx] = f2bf(fmaxf(acc1[reg] + bo, 0.0f));
        }
    }
}

// ---- layer 3 GEMM + fused head -------------------------------------------
// Block = 64 rows x ALL 128 cols (782 blocks, 3.05/CU). Two LDS phases
// (32KB): stage W half, compute its 4 N-frags, accumulate head partials
// in-register, barrier, restage other half. h3 never hits global. Head dot
// closed by a 16-lane shfl_xor tree; r==0 lanes write out[row][0..3].
__global__ __launch_bounds__(256) void layer128_head_kernel(
    const bf16_t* __restrict__ aggb, const bf16_t* __restrict__ hin,
    const float* __restrict__ Wl, const float* __restrict__ Wr,
    const float* __restrict__ bias, const float* __restrict__ Wh,
    const float* __restrict__ bh, float* __restrict__ out, int n) {
    __shared__ bf16_t w_lds[16384];          // 32KB

    const int t = threadIdx.x;
    const int lane = t & 63;
    const int wave = t >> 6;
    const int r = lane & 15;
    const int q = lane >> 4;
    const int m0w = blockIdx.x * 64 + wave * 16;   // 4 waves x 16 rows

    // A fragments for full K=256 (loaded once), one 16-row M-frag per wave
    bf16x8 aF[8];
    {
        int node = m0w + r;
        if (node >= n) node = n - 1;
        const bf16_t* arow = aggb + (size_t)node * 128;
        const bf16_t* hrow = hin + (size_t)node * 128;
        #pragma unroll
        for (int ks = 0; ks < 4; ++ks)
            aF[ks] = *(const bf16x8*)(arow + ks * 32 + q * 8);
        #pragma unroll
        for (int ks = 0; ks < 4; ++ks)
            aF[4 + ks] = *(const bf16x8*)(hrow + ks * 32 + q * 8);
    }

    float p[4][4];                           // [reg][o] head partials
    #pragma unroll
    for (int reg = 0; reg < 4; ++reg)
        #pragma unroll
        for (int o = 0; o < 4; ++o) p[reg][o] = 0.f;

    #pragma unroll
    for (int phase = 0; phase < 2; ++phase) {
        if (phase) __syncthreads();          // all reads of phase-0 W done
        const int nbase = phase * 64;
        #pragma unroll
        for (int i = 0; i < 8; ++i) {
            int ch  = i * 256 + t;
            int q_  = ch & 3;
            int r_  = (ch >> 2) & 15;
            int ks_ = (ch >> 6) & 7;
            int nt_ = ch >> 9;
            int cidx = nbase + nt_ * 16 + r_;
            int k0 = ks_ * 32 + q_ * 8;
            const float* src = (k0 < 128) ? (Wl + cidx * 128 + k0)
                                          : (Wr + cidx * 128 + (k0 - 128));
            float4 a = *(const float4*)src;
            float4 b = *(const float4*)(src + 4);
            uint4 pk;
            pk.x = (uint32)f2bf(a.x) | ((uint32)f2bf(a.y) << 16);
            pk.y = (uint32)f2bf(a.z) | ((uint32)f2bf(a.w) << 16);
            pk.z = (uint32)f2bf(b.x) | ((uint32)f2bf(b.y) << 16);
            pk.w = (uint32)f2bf(b.z) | ((uint32)f2bf(b.w) << 16);
            *(uint4*)&w_lds[ch * 8] = pk;
        }
        __syncthreads();

        #pragma unroll
        for (int nt = 0; nt < 4; ++nt) {
            f32x4 acc0 = {0.f, 0.f, 0.f, 0.f};
            #pragma unroll
            for (int ks = 0; ks < 8; ++ks) {
                bf16x8 bF = *(const bf16x8*)&w_lds[(size_t)((nt * 8 + ks) * 64 + r * 4 + q) * 8];
                acc0 = __builtin_amdgcn_mfma_f32_16x16x32_bf16(aF[ks], bF, acc0, 0, 0, 0);
            }
            const int cidx = nbase + nt * 16 + r;
            const float bo = bias[cidx];
            const float wh0 = Wh[cidx], wh1 = Wh[128 + cidx];
            const float wh2 = Wh[256 + cidx], wh3 = Wh[384 + cidx];
            #pragma unroll
            for (int reg = 0; reg < 4; ++reg) {
                float h0 = fmaxf(acc0[reg] + bo, 0.0f);
                p[reg][0] += h0 * wh0; p[reg][1] += h0 * wh1;
                p[reg][2] += h0 * wh2; p[reg][3] += h0 * wh3;
            }
        }
    }

    // close the col-dot: reduce over the 16 r-lanes; r==0 writes 4 outs/row
    #pragma unroll
    for (int reg = 0; reg < 4; ++reg)
        #pragma unroll
        for (int o = 0; o < 4; ++o) {
            float v = p[reg][o];
            v += __shfl_xor(v, 1);
            v += __shfl_xor(v, 2);
            v += __shfl_xor(v, 4);
            v += __shfl_xor(v, 8);
            if (r == 0) {
                int row = m0w + q * 4 + reg;
                if (row < n) out[(size_t)row * 4 + o] = v + bh[o];
            }
        }
}

extern "C" void kernel_launch(void* const* d_in, const int* in_sizes, int n_in,
                              void* d_out, int out_size, void* d_ws, size_t ws_size,
                              hipStream_t stream) {
    const float* x   = (const float*)d_in[0];
    const int*   ei  = (const int*)d_in[1];
    const float* Wl1 = (const float*)d_in[2];
    const float* Wr1 = (const float*)d_in[3];
    const float* b1  = (const float*)d_in[4];
    const float* Wl2 = (const float*)d_in[5];
    const float* Wr2 = (const float*)d_in[6];
    const float* b2  = (const float*)d_in[7];
    const float* Wl3 = (const float*)d_in[8];
    const float* Wr3 = (const float*)d_in[9];
    const float* b3  = (const float*)d_in[10];
    const float* Wh  = (const float*)d_in[11];
    const float* bh  = (const float*)d_in[12];
    float* out = (float*)d_out;

    const int N = in_sizes[0] / 16;
    const int E = in_sizes[1] / 2;
    const int* src = ei;
    const int* dst = ei + E;

    int* cnt       = (int*)d_ws;                       // N
    int* colp      = cnt + ((N + 64) & ~63);           // N*DEG_SLOTS (aligned)
    bf16_t* aggb   = (bf16_t*)(colp + (size_t)N * DEG_SLOTS);  // N*128 bf16
    bf16_t* hA     = aggb + (size_t)N * 128;           // N*128 bf16
    bf16_t* hB     = hA + (size_t)N * 128;             // N*128 bf16

    const int B = 256;
    auto blocks = [](long total, int b) { return (int)((total + b - 1) / b); };

    // ---- padded CSR build: async memset + vectorized fill ----
    hipMemsetAsync(cnt, 0, (size_t)N * sizeof(int), stream);
    fill_padded_kernel<<<blocks((E + 3) / 4, B), B, 0, stream>>>(src, dst, cnt, colp, E);

    // ---- layer 1: fused x-gather + MFMA (K=32), writes hA ----
    layer16_fused_kernel<<<blocks(N, 32), B, 0, stream>>>(
        x, cnt, colp, Wl1, Wr1, b1, hA, N);

    // ---- layer 2: aggregate + staged MFMA GEMM, writes hB ----
    aggregate128_kernel<<<blocks(N, 8), B, 0, stream>>>(hA, cnt, colp, aggb, N);
    layer128_mfma_kernel<<<2 * blocks(N, 128), B, 0, stream>>>(
        aggb, hA, Wl2, Wr2, b2, hB, N);

    // ---- layer 3 GEMM + head fused (64-row blocks), writes out directly ----
    aggregate128_kernel<<<blocks(N, 8), B, 0, stream>>>(hB, cnt, colp, aggb, N);
    layer128_head_kernel<<<blocks(N, 64), B, 0, stream>>>(
        aggb, hB, Wl3, Wr3, b3, Wh, bh, out, N);
}